// Round 15
// baseline (856.157 us; speedup 1.0000x reference)
//
#include <hip/hip_runtime.h>
#include <hip/hip_bf16.h>
#include <math.h>

#define PSPLIT 8
#define BSH 6                  // bucket = dst >> BSH  (64 dsts/bucket)
#define BW 64
#define AST 40                 // LDS row stride in shorts (80B: 16B-aligned, 2-way banks max)

typedef float v4f __attribute__((ext_vector_type(4)));
typedef unsigned int v4u __attribute__((ext_vector_type(4)));
typedef __attribute__((ext_vector_type(8))) short bf8;
typedef __attribute__((ext_vector_type(4))) float f4;
typedef unsigned short u16;
typedef unsigned int u32;

static inline size_t align_up(size_t x, size_t a){ return (x + a - 1) & ~(a - 1); }

__device__ inline void bf_split(float v, u16& hi, u16& lo){
  __hip_bfloat16 h = __float2bfloat16(v);
  float hf = __bfloat162float(h);
  __hip_bfloat16 l = __float2bfloat16(v - hf);
  hi = *(u16*)&h; lo = *(u16*)&l;
}

// ---------------- graph prep: bucketed CSR build (+ fused gstart + fused cvtw) ----------------

__global__ __launch_bounds__(256) void k_bhist(const int* __restrict__ col, int* __restrict__ bcnt,
                                               int E, int NB,
                                               const int* __restrict__ batch, int* __restrict__ gstart,
                                               int n, int G,
                                               const float* __restrict__ w0, const float* __restrict__ w1,
                                               const float* __restrict__ w2, const float* __restrict__ w3,
                                               u16* __restrict__ wf){
  extern __shared__ int lh[];
  for (int i = threadIdx.x; i < NB; i += 256) lh[i] = 0;
  __syncthreads();
  for (int e = blockIdx.x * 256 + threadIdx.x; e < E; e += gridDim.x * 256)
    atomicAdd(&lh[col[e] >> BSH], 1);
  __syncthreads();
  for (int i = threadIdx.x; i < NB; i += 256){
    int v = lh[i];
    if (v) atomicAdd(&bcnt[i], v);
  }
  // fused gstart
  for (int i = blockIdx.x * 256 + threadIdx.x; i < n; i += gridDim.x * 256){
    int cb = batch[i];
    if (i == 0){ for (int g = 0; g <= cb; ++g) gstart[g] = 0; }
    else { int pb = batch[i - 1]; for (int g = pb + 1; g <= cb; ++g) gstart[g] = i; }
    if (i == n - 1){ for (int g = cb + 1; g <= G; ++g) gstart[g] = n; }
  }
  // fused W conversion: f32 [k][n] -> per-lane MFMA B-frag layout
  // wf[l][c][nt][plane][lane][8 u16]
  for (int id = blockIdx.x * 256 + threadIdx.x; id < 16384; id += gridDim.x * 256){
    int lane = id & 63;
    int pl   = (id >> 6) & 1;
    int nt   = (id >> 7) & 7;
    int c    = (id >> 10) & 3;
    int l    = id >> 12;
    const float* Wsrc = (l == 0) ? w0 : (l == 1) ? w1 : (l == 2) ? w2 : w3;
    int nn = nt * 16 + (lane & 15);
    int k0 = c * 32 + (lane >> 4) * 8;
    bf8 o;
    #pragma unroll
    for (int j = 0; j < 8; ++j){
      float v = Wsrc[(k0 + j) * 128 + nn];
      u16 hi, lo; bf_split(v, hi, lo);
      o[j] = (short)(pl ? lo : hi);
    }
    *(bf8*)(wf + (size_t)id * 8) = o;
  }
}

__global__ void k_bscan(const int* __restrict__ bcnt, int* __restrict__ boff, int NB, int E,
                        int* __restrict__ rp, int N){
  __shared__ int sd[256];
  int t = threadIdx.x;
  int c[16]; int s = 0;
  const int PT = (NB + 255) / 256;   // <= 16
  for (int j = 0; j < PT; ++j){ int i = t * PT + j; c[j] = (i < NB) ? bcnt[i] : 0; s += c[j]; }
  sd[t] = s; __syncthreads();
  for (int off = 1; off < 256; off <<= 1){
    int v = sd[t];
    if (t >= off) v += sd[t - off];
    __syncthreads(); sd[t] = v; __syncthreads();
  }
  int run = sd[t] - s;
  for (int j = 0; j < PT; ++j){ int i = t * PT + j; if (i < NB) boff[i] = run; run += c[j]; }
  if (t == 255){ boff[NB] = run; rp[N] = E; }
}

__global__ __launch_bounds__(256) void k_bscat(const int* __restrict__ ei, const int* __restrict__ boff,
                                               int* __restrict__ bfill, unsigned* __restrict__ tmp, int E){
  int e = blockIdx.x * 256 + threadIdx.x;
  if (e >= E) return;
  int s = ei[e], d = ei[E + e];
  int b = d >> BSH;
  int p = atomicAdd(&bfill[b * 32], 1);          // full-line-padded counter (128B)
  tmp[boff[b] + p] = (unsigned)s | ((unsigned)(d & (BW - 1)) << 17);
}

__global__ __launch_bounds__(256) void k_bfin(const unsigned* __restrict__ tmp, const int* __restrict__ boff,
                                              int* __restrict__ ssrc, int* __restrict__ rp,
                                              float* __restrict__ dinv, int N){
  int b = blockIdx.x;
  int d0 = b << BSH;
  int lim = N - d0; if (lim > BW) lim = BW;
  __shared__ int dcnt[BW], dst_[BW], lfill[BW];
  int t = threadIdx.x;
  if (t < BW){ dcnt[t] = 0; lfill[t] = 0; }
  __syncthreads();
  int lo = boff[b], hi = boff[b + 1];
  for (int i = lo + t; i < hi; i += 256) atomicAdd(&dcnt[tmp[i] >> 17], 1);
  __syncthreads();
  if (t == 0){ int run = 0; for (int l = 0; l < BW; ++l){ dst_[l] = run; run += dcnt[l]; } }
  __syncthreads();
  if (t < lim){
    int d = d0 + t;
    rp[d] = lo + dst_[t];
    double dd = (double)(dcnt[t] + 1);           // +1 self-loop
    dinv[d] = (float)(1.0 / sqrt(dd));
  }
  __syncthreads();
  for (int i = lo + t; i < hi; i += 256){
    unsigned r = tmp[i];
    int l = r >> 17;
    int pos = dst_[l] + atomicAdd(&lfill[l], 1);
    ssrc[lo + pos] = (int)(r & 0x1FFFFu);
  }
}

// ---------------- GEMM (MFMA hybrid + LDS double-buffer): C = (A @ W) * dinv[row] ----------------
// Split-bf16 3-term (hi*hi + lo*hi + hi*lo). A staged via LDS double-buffer (one barrier
// per chunk; next chunk's global loads issued BEFORE the sync so latency overlaps
// barrier-wait + MFMA); W frags direct from global in lane-ordered frag layout (1KB
// contiguous per wave-load, 128KB L2-resident). LDS 40KB -> 4 blocks/CU.
// 128 rows/block, 4 waves x 2 m-tiles, 8 n-tiles, K in 4x32 chunks.
// packed=1: A is u32 (bf16hi<<16|bf16lo) from agg; packed=0: f32 (layer 0).
// Frag layouts m89/m91-verified: A[m=lane&15][k=quad*8+j]; D col=lane&15,row=quad*4+reg.

__global__ __launch_bounds__(256, 4) void k_gemm(const float* __restrict__ A,
                                                 const u16* __restrict__ wf,
                                                 const float* __restrict__ dinv,
                                                 float* __restrict__ C, int n, int packed){
  __shared__ u16 Ah[2][128 * AST], Al[2][128 * AST];
  int t = threadIdx.x;
  int r0 = blockIdx.x * 128;
  int wv = t >> 6, lane = t & 63;
  int q = lane >> 4, ln = lane & 15;
  const bf8* wfv = (const bf8*)wf;

  int srow = t >> 1;               // 0..127
  int shalf = (t & 1) * 16;        // k-offset within 32-chunk
  int grow = r0 + srow; if (grow > n - 1) grow = n - 1;
  const float* ga = A + (size_t)grow * 128 + shalf;

  u32 uxs[16];
  float fxs[16];
  auto ldc = [&](int c){
    if (packed){
      const v4u* gp = (const v4u*)(ga + c * 32);
      #pragma unroll
      for (int i = 0; i < 4; ++i){
        v4u v = gp[i];
        uxs[i*4] = v.x; uxs[i*4+1] = v.y; uxs[i*4+2] = v.z; uxs[i*4+3] = v.w;
      }
    } else {
      const float4* gp = (const float4*)(ga + c * 32);
      #pragma unroll
      for (int i = 0; i < 4; ++i){
        float4 v = gp[i];
        fxs[i*4] = v.x; fxs[i*4+1] = v.y; fxs[i*4+2] = v.z; fxs[i*4+3] = v.w;
      }
    }
  };
  auto stg = [&](int b){
    u16* ah = &Ah[b][srow * AST + shalf];
    u16* al = &Al[b][srow * AST + shalf];
    #pragma unroll
    for (int i = 0; i < 4; ++i){
      u16 h[4], l[4];
      #pragma unroll
      for (int j = 0; j < 4; ++j){
        if (packed){ u32 u = uxs[i*4+j]; h[j] = (u16)(u >> 16); l[j] = (u16)u; }
        else { bf_split(fxs[i*4+j], h[j], l[j]); }
      }
      ushort4 hv = {h[0],h[1],h[2],h[3]}, lv = {l[0],l[1],l[2],l[3]};
      *(ushort4*)&ah[i*4] = hv;
      *(ushort4*)&al[i*4] = lv;
    }
  };

  f4 acc[2][8];
  #pragma unroll
  for (int mt = 0; mt < 2; ++mt)
    #pragma unroll
    for (int nt = 0; nt < 8; ++nt) acc[mt][nt] = (f4)(0.f);

  ldc(0); stg(0);
  for (int c = 0; c < 4; ++c){
    if (c < 3) ldc(c + 1);               // in flight across barrier + MFMA
    __syncthreads();                     // publish buf[c&1]
    int b = c & 1;
    bf8 afh[2], afl[2];
    #pragma unroll
    for (int mt = 0; mt < 2; ++mt){
      int row = wv * 32 + mt * 16 + ln;
      afh[mt] = *(const bf8*)&Ah[b][row * AST + q * 8];
      afl[mt] = *(const bf8*)&Al[b][row * AST + q * 8];
    }
    #pragma unroll
    for (int nt = 0; nt < 8; ++nt){
      bf8 wfh = wfv[(size_t)((c * 8 + nt) * 2 + 0) * 64 + lane];
      bf8 wfl = wfv[(size_t)((c * 8 + nt) * 2 + 1) * 64 + lane];
      #pragma unroll
      for (int mt = 0; mt < 2; ++mt){
        acc[mt][nt] = __builtin_amdgcn_mfma_f32_16x16x32_bf16(afh[mt], wfh, acc[mt][nt], 0, 0, 0);
        acc[mt][nt] = __builtin_amdgcn_mfma_f32_16x16x32_bf16(afl[mt], wfh, acc[mt][nt], 0, 0, 0);
        acc[mt][nt] = __builtin_amdgcn_mfma_f32_16x16x32_bf16(afh[mt], wfl, acc[mt][nt], 0, 0, 0);
      }
    }
    if (c < 3) stg((c + 1) & 1);         // disjoint buffer: no extra barrier needed
  }

  // epilogue: D row = quad*4+reg, col = nt*16+ln; scale by dinv[row]
  #pragma unroll
  for (int mt = 0; mt < 2; ++mt){
    int base_m = r0 + wv * 32 + mt * 16 + q * 4;
    float dv[4];
    #pragma unroll
    for (int reg = 0; reg < 4; ++reg){
      int row = base_m + reg;
      dv[reg] = (row < n) ? dinv[row] : 0.f;
    }
    #pragma unroll
    for (int nt = 0; nt < 8; ++nt){
      #pragma unroll
      for (int reg = 0; reg < 4; ++reg){
        int row = base_m + reg;
        if (row < n) C[(size_t)row * 128 + nt * 16 + ln] = acc[mt][nt][reg] * dv[reg];
      }
    }
  }
}

// ---------------- aggregate: h_out = tanh(dinv[d]*(sum hw'[src] + hw'[d]) + b) ----------------
// R6 memory structure (do not perturb): one wave per (node, feature-half); quarter-wave
// per edge (float4/lane, 256B coalesced), 64-edge meta loads, 16-edge unroll.
// At the Infinity-Cache read roofline (~3.84 TB/s L2-fill, 372MB compulsory).
// pack=1: write h as (bf16hi<<16)|bf16lo u32; pack=0 (last layer): f32 for pool.

__global__ __launch_bounds__(256) void k_agg(const float* __restrict__ hwp, const int* __restrict__ rp,
                                             const int* __restrict__ ssrc,
                                             const float* __restrict__ dinv, const float* __restrict__ bias,
                                             float* __restrict__ hout, int n, int pack){
  int b = blockIdx.x;
  int r = b & 7;
  int F = r >> 2;                       // feature half
  int s = (b >> 3) * 4 + (r & 3);       // slot of 4 nodes
  int node = s * 4 + (threadIdx.x >> 6);
  if (node >= n) return;
  int lane = threadIdx.x & 63;
  int ql = lane >> 4;                   // edge slot 0..3
  int fl = lane & 15;                   // feature quad within half
  const v4f* base = (const v4f*)hwp + F * 16 + fl;   // row stride = 32 v4f

  int e0 = rp[node], e1 = rp[node + 1];
  v4f acc = (v4f)(0.f);
  for (int eb = e0; eb < e1; eb += 64){
    int m = e1 - eb; if (m > 64) m = 64;
    int sl = (lane < m) ? ssrc[eb + lane] : 0;
    int mp = m & ~3;
    int j = 0;
    for (; j + 16 <= mp; j += 16){
      int s0 = __shfl(sl, j + ql),     s1 = __shfl(sl, j + 4 + ql);
      int s2 = __shfl(sl, j + 8 + ql), s3 = __shfl(sl, j + 12 + ql);
      v4f v0 = base[(size_t)s0 * 32], v1 = base[(size_t)s1 * 32];
      v4f v2 = base[(size_t)s2 * 32], v3 = base[(size_t)s3 * 32];
      acc += v0; acc += v1; acc += v2; acc += v3;
    }
    if (j + 8 <= mp){
      int s0 = __shfl(sl, j + ql), s1 = __shfl(sl, j + 4 + ql);
      v4f v0 = base[(size_t)s0 * 32], v1 = base[(size_t)s1 * 32];
      acc += v0; acc += v1;
      j += 8;
    }
    if (j + 4 <= mp){
      int s0 = __shfl(sl, j + ql);
      acc += base[(size_t)s0 * 32];
      j += 4;
    }
    if (j < m){
      int s0 = __shfl(sl, j + ql);
      if (j + ql < m){
        acc += base[(size_t)s0 * 32];
      }
    }
  }
  // reduce across the 4 edge slots
  acc.x += __shfl_down(acc.x, 32); acc.y += __shfl_down(acc.y, 32);
  acc.z += __shfl_down(acc.z, 32); acc.w += __shfl_down(acc.w, 32);
  acc.x += __shfl_down(acc.x, 16); acc.y += __shfl_down(acc.y, 16);
  acc.z += __shfl_down(acc.z, 16); acc.w += __shfl_down(acc.w, 16);
  if (lane < 16){
    acc += base[(size_t)node * 32];          // self term (already * dinv[node])
    float di = dinv[node];
    int f = F * 64 + fl * 4;
    v4f bv = *(const v4f*)(bias + f);
    float r0 = tanhf(acc.x * di + bv.x);
    float r1 = tanhf(acc.y * di + bv.y);
    float r2 = tanhf(acc.z * di + bv.z);
    float r3 = tanhf(acc.w * di + bv.w);
    if (pack){
      u16 h0,h1,h2,h3,l0,l1,l2,l3;
      bf_split(r0, h0, l0); bf_split(r1, h1, l1);
      bf_split(r2, h2, l2); bf_split(r3, h3, l3);
      v4u pv;
      pv.x = ((u32)h0 << 16) | l0; pv.y = ((u32)h1 << 16) | l1;
      pv.z = ((u32)h2 << 16) | l2; pv.w = ((u32)h3 << 16) | l3;
      __builtin_nontemporal_store(pv, (v4u*)(hout + (size_t)node * 128 + f));
    } else {
      v4f rr; rr.x = r0; rr.y = r1; rr.z = r2; rr.w = r3;
      __builtin_nontemporal_store(rr, (v4f*)(hout + (size_t)node * 128 + f));
    }
  }
}

// ---------------- pool: stage 1 partial max/sum (float4 lanes, 8 rows/iter) ----------------

__global__ __launch_bounds__(256) void k_pool1(const float* __restrict__ h, const int* __restrict__ gstart,
                                               float* __restrict__ pmx, float* __restrict__ psm){
  int g = blockIdx.x >> 3, s = blockIdx.x & (PSPLIT - 1);
  int t = threadIdx.x;
  int fq = t & 31;             // feature quad
  int rw = t >> 5;             // row slot 0..7
  int i0 = gstart[g], i1 = gstart[g + 1];
  int len = i1 - i0;
  int chunk = (len + PSPLIT - 1) / PSPLIT;
  int a = i0 + s * chunk;
  int b = a + chunk; if (b > i1) b = i1;

  const v4f* hv = (const v4f*)h;
  v4f mx = (v4f)(-INFINITY), sm = (v4f)(0.f);
  for (int i = a + rw; i < b; i += 8){
    v4f v = hv[(size_t)i * 32 + fq];
    mx.x = fmaxf(mx.x, v.x); mx.y = fmaxf(mx.y, v.y);
    mx.z = fmaxf(mx.z, v.z); mx.w = fmaxf(mx.w, v.w);
    sm += v;
  }
  __shared__ v4f smx[8][32], ssm[8][32];
  smx[rw][fq] = mx; ssm[rw][fq] = sm;
  __syncthreads();
  if (rw == 0){
    #pragma unroll
    for (int r2 = 1; r2 < 8; ++r2){
      v4f m2 = smx[r2][fq], s2 = ssm[r2][fq];
      mx.x = fmaxf(mx.x, m2.x); mx.y = fmaxf(mx.y, m2.y);
      mx.z = fmaxf(mx.z, m2.z); mx.w = fmaxf(mx.w, m2.w);
      sm += s2;
    }
    ((v4f*)pmx)[(size_t)blockIdx.x * 32 + fq] = mx;
    ((v4f*)psm)[(size_t)blockIdx.x * 32 + fq] = sm;
  }
}

__global__ __launch_bounds__(128) void k_head(const float* __restrict__ pmx, const float* __restrict__ psm,
                                              const int* __restrict__ gstart,
                                              const float* __restrict__ Wl, const float* __restrict__ bl,
                                              float* __restrict__ out){
  int g = blockIdx.x, f = threadIdx.x;
  float mx = -INFINITY, sm = 0.f;
  #pragma unroll
  for (int s = 0; s < PSPLIT; ++s){
    mx = fmaxf(mx, pmx[((size_t)g * PSPLIT + s) * 128 + f]);
    sm += psm[((size_t)g * PSPLIT + s) * 128 + f];
  }
  int cnt = gstart[g + 1] - gstart[g];
  if (cnt <= 0) mx = 0.f;
  float mn = sm / (float)(cnt > 0 ? cnt : 1);
  float contrib = mx * Wl[f] + mn * Wl[128 + f];
  for (int o = 32; o > 0; o >>= 1) contrib += __shfl_down(contrib, o);
  __shared__ float sred[2];
  if ((f & 63) == 0) sred[f >> 6] = contrib;
  __syncthreads();
  if (f == 0) out[g] = sred[0] + sred[1] + bl[0];
}

// ---------------- launch ----------------

extern "C" void kernel_launch(void* const* d_in, const int* in_sizes, int n_in,
                              void* d_out, int out_size, void* d_ws, size_t ws_size,
                              hipStream_t stream){
  const float* x     = (const float*)d_in[0];
  const int*   ei    = (const int*)d_in[1];
  const int*   batch = (const int*)d_in[2];
  const float* W[4]  = {(const float*)d_in[3], (const float*)d_in[5], (const float*)d_in[7], (const float*)d_in[9]};
  const float* B[4]  = {(const float*)d_in[4], (const float*)d_in[6], (const float*)d_in[8], (const float*)d_in[10]};
  const float* Wl    = (const float*)d_in[11];
  const float* bl    = (const float*)d_in[12];
  float* out = (float*)d_out;

  int N = in_sizes[0] / 128;
  int E = in_sizes[1] / 2;
  int G = out_size;
  int NB = (N + BW - 1) >> BSH;

  char* ws = (char*)d_ws;
  size_t off = 0;
  auto alloc = [&](size_t bytes) -> void* {
    void* p = ws + off; off = align_up(off + bytes, 256); return p;
  };
  float* dinv  = (float*)alloc((size_t)N * 4);
  int*   rp    = (int*)  alloc((size_t)(N + 1) * 4);
  int*   bcnt  = (int*)  alloc((size_t)(NB + 1) * 4);
  int*   boff  = (int*)  alloc((size_t)(NB + 1) * 4);
  int*   bfill = (int*)  alloc((size_t)NB * 32 * 4);
  int*   gst   = (int*)  alloc((size_t)(G + 1) * 4);
  int*   ssrc  = (int*)  alloc((size_t)E * 4);
  u16*   wf    = (u16*)  alloc((size_t)4 * 32768 * 2);   // per-layer 64KB frag-layout W
  float* pmx   = (float*)alloc((size_t)G * PSPLIT * 128 * 4);
  float* psm   = (float*)alloc((size_t)G * PSPLIT * 128 * 4);
  float* hw    = (float*)alloc((size_t)N * 128 * 4);
  float* h     = (float*)alloc((size_t)N * 128 * 4);
  unsigned* tmp = (unsigned*)hw;   // alias: tmp dead before first gemm writes hw

  hipMemsetAsync(bcnt, 0, (size_t)(NB + 1) * 4, stream);
  hipMemsetAsync(bfill, 0, (size_t)NB * 32 * 4, stream);

  int gE = (E + 255) / 256;
  k_bhist<<<128, 256, NB * 4, stream>>>(ei + E, bcnt, E, NB, batch, gst, N, G,
                                        W[0], W[1], W[2], W[3], wf);
  k_bscan<<<1, 256, 0, stream>>>(bcnt, boff, NB, E, rp, N);
  k_bscat<<<gE, 256, 0, stream>>>(ei, boff, bfill, tmp, E);
  k_bfin <<<NB, 256, 0, stream>>>(tmp, boff, ssrc, rp, dinv, N);

  int gemmG = (N + 127) / 128;
  int slots = (N + 3) / 4;                 // (node-quad) slots per feature half
  int aggG  = 8 * ((slots + 3) / 4);       // 2-way static feature split
  const float* hin = x;
  for (int l = 0; l < 4; ++l){
    k_gemm<<<gemmG, 256, 0, stream>>>(hin, wf + (size_t)l * 32768, dinv, hw, N, l > 0);
    k_agg <<<aggG, 256, 0, stream>>>(hw, rp, ssrc, dinv, B[l], h, N, l < 3);
    hin = h;
  }
  k_pool1<<<G * PSPLIT, 256, 0, stream>>>(h, gst, pmx, psm);
  k_head <<<G, 128, 0, stream>>>(pmx, psm, gst, Wl, bl, out);
}

// Round 16
// 793.828 us; speedup vs baseline: 1.0785x; 1.0785x over previous
//
#include <hip/hip_runtime.h>
#include <hip/hip_bf16.h>
#include <math.h>

#define PSPLIT 8
#define BSH 5                  // bucket = dst >> BSH  (32 dsts/bucket)
#define BW 32
#define AST 40                 // LDS row stride in shorts (80B: 16B-aligned, 2-way banks max)

typedef float v4f __attribute__((ext_vector_type(4)));
typedef unsigned int v4u __attribute__((ext_vector_type(4)));
typedef __attribute__((ext_vector_type(8))) short bf8;
typedef __attribute__((ext_vector_type(4))) float f4;
typedef unsigned short u16;
typedef unsigned int u32;

static inline size_t align_up(size_t x, size_t a){ return (x + a - 1) & ~(a - 1); }

__device__ inline void bf_split(float v, u16& hi, u16& lo){
  __hip_bfloat16 h = __float2bfloat16(v);
  float hf = __bfloat162float(h);
  __hip_bfloat16 l = __float2bfloat16(v - hf);
  hi = *(u16*)&h; lo = *(u16*)&l;
}

// ---------------- graph prep: bucketed CSR build ----------------

__global__ __launch_bounds__(256) void k_bhist(const int* __restrict__ col, int* __restrict__ bcnt,
                                               int E, int NB,
                                               const int* __restrict__ batch, int* __restrict__ gstart,
                                               int n, int G){
  extern __shared__ int lh[];
  for (int i = threadIdx.x; i < NB; i += 256) lh[i] = 0;
  __syncthreads();
  for (int e = blockIdx.x * 256 + threadIdx.x; e < E; e += gridDim.x * 256)
    atomicAdd(&lh[col[e] >> BSH], 1);
  __syncthreads();
  for (int i = threadIdx.x; i < NB; i += 256){
    int v = lh[i];
    if (v) atomicAdd(&bcnt[i], v);
  }
  // fused gstart
  for (int i = blockIdx.x * 256 + threadIdx.x; i < n; i += gridDim.x * 256){
    int cb = batch[i];
    if (i == 0){ for (int g = 0; g <= cb; ++g) gstart[g] = 0; }
    else { int pb = batch[i - 1]; for (int g = pb + 1; g <= cb; ++g) gstart[g] = i; }
    if (i == n - 1){ for (int g = cb + 1; g <= G; ++g) gstart[g] = n; }
  }
}

__global__ void k_bscan(const int* __restrict__ bcnt, int* __restrict__ boff, int NB, int E,
                        int* __restrict__ rp, int N){
  __shared__ int sd[256];
  int t = threadIdx.x;
  int c[16]; int s = 0;
  const int PT = (NB + 255) / 256;   // <= 16
  for (int j = 0; j < PT; ++j){ int i = t * PT + j; c[j] = (i < NB) ? bcnt[i] : 0; s += c[j]; }
  sd[t] = s; __syncthreads();
  for (int off = 1; off < 256; off <<= 1){
    int v = sd[t];
    if (t >= off) v += sd[t - off];
    __syncthreads(); sd[t] = v; __syncthreads();
  }
  int run = sd[t] - s;
  for (int j = 0; j < PT; ++j){ int i = t * PT + j; if (i < NB) boff[i] = run; run += c[j]; }
  if (t == 255){ boff[NB] = run; rp[N] = E; }
}

__global__ __launch_bounds__(256) void k_bscat(const int* __restrict__ ei, const int* __restrict__ boff,
                                               int* __restrict__ bfill, unsigned* __restrict__ tmp, int E){
  int e = blockIdx.x * 256 + threadIdx.x;
  if (e >= E) return;
  int s = ei[e], d = ei[E + e];
  int b = d >> BSH;
  int p = atomicAdd(&bfill[b * 32], 1);          // full-line-padded counter (128B)
  tmp[boff[b] + p] = (unsigned)s | ((unsigned)(d & (BW - 1)) << 17);
}

__global__ __launch_bounds__(256) void k_bfin(const unsigned* __restrict__ tmp, const int* __restrict__ boff,
                                              int* __restrict__ ssrc, int* __restrict__ rp,
                                              float* __restrict__ dinv, int N){
  int b = blockIdx.x;
  int d0 = b << BSH;
  int lim = N - d0; if (lim > BW) lim = BW;
  __shared__ int dcnt[BW], dst_[BW], lfill[BW];
  int t = threadIdx.x;
  if (t < BW){ dcnt[t] = 0; lfill[t] = 0; }
  __syncthreads();
  int lo = boff[b], hi = boff[b + 1];
  for (int i = lo + t; i < hi; i += 256) atomicAdd(&dcnt[tmp[i] >> 17], 1);
  __syncthreads();
  if (t == 0){ int run = 0; for (int l = 0; l < BW; ++l){ dst_[l] = run; run += dcnt[l]; } }
  __syncthreads();
  if (t < lim){
    int d = d0 + t;
    rp[d] = lo + dst_[t];
    double dd = (double)(dcnt[t] + 1);           // +1 self-loop
    dinv[d] = (float)(1.0 / sqrt(dd));
  }
  __syncthreads();
  for (int i = lo + t; i < hi; i += 256){
    unsigned r = tmp[i];
    int l = r >> 17;
    int pos = dst_[l] + atomicAdd(&lfill[l], 1);
    ssrc[lo + pos] = (int)(r & 0x1FFFFu);
  }
}

// ---------------- W conversion: f32 [k][n] -> bf16 hi/lo TRANSPOSED [l][n][k] ----------------

__global__ __launch_bounds__(256) void k_cvtw(const float* __restrict__ w0, const float* __restrict__ w1,
                                              const float* __restrict__ w2, const float* __restrict__ w3,
                                              u16* __restrict__ wth, u16* __restrict__ wtl){
  int id = blockIdx.x * 256 + threadIdx.x;
  if (id >= 4 * 16384) return;
  int l = id >> 14, rem = id & 16383, k = rem >> 7, nn = rem & 127;
  const float* Wsrc = (l == 0) ? w0 : (l == 1) ? w1 : (l == 2) ? w2 : w3;
  float v = Wsrc[k * 128 + nn];
  u16 hi, lo; bf_split(v, hi, lo);
  wth[(l << 14) + nn * 128 + k] = hi;
  wtl[(l << 14) + nn * 128 + k] = lo;
}

// ---------------- GEMM (MFMA): C[N,128] = (A[N,128] @ W[128,128]) * dinv[row] ----------------
// R12 measured-best structure (797us). Split-bf16, 3-term MFMA (lo*lo ~1e-6 dropped).
// packed=0: A is f32 (layer 0, split in staging). packed=1: A is u32 (hi<<16|lo) from agg.
// 128-row tile, 4 waves x 32 rows, 8 n-tiles, K in 4 chunks of 32. LDS 40KB -> 4 blocks/CU.
// Frag layouts (m89/m91-verified): A[m=lane&15][k=quad*8+j]; B via W^T rows; D row=quad*4+reg.

__global__ __launch_bounds__(256, 4) void k_gemm(const float* __restrict__ A,
                                                 const u16* __restrict__ wth, const u16* __restrict__ wtl,
                                                 const float* __restrict__ dinv,
                                                 float* __restrict__ C, int n, int packed){
  __shared__ u16 Ah[128 * AST], Al[128 * AST], Wh[128 * AST], Wl[128 * AST];
  int t = threadIdx.x;
  int r0 = blockIdx.x * 128;
  int wv = t >> 6, lane = t & 63;
  int q = lane >> 4, ln = lane & 15;

  int srow = t >> 1;               // 0..127
  int shalf = (t & 1) * 16;        // k-offset within 32-chunk
  int grow = r0 + srow; if (grow > n - 1) grow = n - 1;
  const float* ga = A + (size_t)grow * 128 + shalf;
  const u16* gwh = wth + srow * 128 + shalf;
  const u16* gwl = wtl + srow * 128 + shalf;

  f4 acc[2][8];
  #pragma unroll
  for (int mt = 0; mt < 2; ++mt)
    #pragma unroll
    for (int nt = 0; nt < 8; ++nt) acc[mt][nt] = (f4)(0.f);

  for (int c = 0; c < 4; ++c){
    __syncthreads();
    // stage A chunk: 16 elems per thread -> hi/lo bf16 planes
    {
      u16* ah = &Ah[srow * AST + shalf];
      u16* al = &Al[srow * AST + shalf];
      if (packed){
        const v4u* gp = (const v4u*)(ga + c * 32);
        #pragma unroll
        for (int i = 0; i < 4; ++i){
          v4u v = gp[i];
          ushort4 hv = {(u16)(v.x >> 16), (u16)(v.y >> 16), (u16)(v.z >> 16), (u16)(v.w >> 16)};
          ushort4 lv = {(u16)v.x, (u16)v.y, (u16)v.z, (u16)v.w};
          *(ushort4*)&ah[i * 4] = hv;
          *(ushort4*)&al[i * 4] = lv;
        }
      } else {
        const float4* gp = (const float4*)(ga + c * 32);
        #pragma unroll
        for (int i = 0; i < 4; ++i){
          float4 v = gp[i];
          u16 h0,h1,h2,h3,l0,l1,l2,l3;
          bf_split(v.x, h0, l0); bf_split(v.y, h1, l1);
          bf_split(v.z, h2, l2); bf_split(v.w, h3, l3);
          ushort4 hv = {h0,h1,h2,h3}, lv = {l0,l1,l2,l3};
          *(ushort4*)&ah[i * 4] = hv;
          *(ushort4*)&al[i * 4] = lv;
        }
      }
    }
    // stage W^T chunk
    {
      const u16* ph = gwh + c * 32;
      const u16* pl = gwl + c * 32;
      bf8 h0 = *(const bf8*)ph, h1 = *(const bf8*)(ph + 8);
      bf8 l0 = *(const bf8*)pl, l1 = *(const bf8*)(pl + 8);
      *(bf8*)&Wh[srow * AST + shalf] = h0; *(bf8*)&Wh[srow * AST + shalf + 8] = h1;
      *(bf8*)&Wl[srow * AST + shalf] = l0; *(bf8*)&Wl[srow * AST + shalf + 8] = l1;
    }
    __syncthreads();

    bf8 afh[2], afl[2];
    #pragma unroll
    for (int mt = 0; mt < 2; ++mt){
      int row = wv * 32 + mt * 16 + ln;
      afh[mt] = *(const bf8*)&Ah[row * AST + q * 8];
      afl[mt] = *(const bf8*)&Al[row * AST + q * 8];
    }
    #pragma unroll
    for (int nt = 0; nt < 8; ++nt){
      int wn = nt * 16 + ln;
      bf8 wfh = *(const bf8*)&Wh[wn * AST + q * 8];
      bf8 wfl = *(const bf8*)&Wl[wn * AST + q * 8];
      #pragma unroll
      for (int mt = 0; mt < 2; ++mt){
        acc[mt][nt] = __builtin_amdgcn_mfma_f32_16x16x32_bf16(afh[mt], wfh, acc[mt][nt], 0, 0, 0);
        acc[mt][nt] = __builtin_amdgcn_mfma_f32_16x16x32_bf16(afl[mt], wfh, acc[mt][nt], 0, 0, 0);
        acc[mt][nt] = __builtin_amdgcn_mfma_f32_16x16x32_bf16(afh[mt], wfl, acc[mt][nt], 0, 0, 0);
      }
    }
  }

  #pragma unroll
  for (int mt = 0; mt < 2; ++mt){
    int base_m = r0 + wv * 32 + mt * 16 + q * 4;
    float dv[4];
    #pragma unroll
    for (int reg = 0; reg < 4; ++reg){
      int row = base_m + reg;
      dv[reg] = (row < n) ? dinv[row] : 0.f;
    }
    #pragma unroll
    for (int nt = 0; nt < 8; ++nt){
      #pragma unroll
      for (int reg = 0; reg < 4; ++reg){
        int row = base_m + reg;
        if (row < n) C[(size_t)row * 128 + nt * 16 + ln] = acc[mt][nt][reg] * dv[reg];
      }
    }
  }
}

// ---------------- aggregate: h_out = tanh(dinv[d]*(sum hw'[src] + hw'[d]) + b) ----------------
// R6 memory structure (do not perturb): one wave per (node, feature-half); quarter-wave
// per edge (float4/lane, 256B coalesced), 64-edge meta loads, 16 gathers in flight.
// At the Infinity-Cache read roofline (~3.84 TB/s L2-fill, 372MB compulsory).
// pack=1: write h as (bf16hi<<16)|bf16lo u32; pack=0 (last layer): f32 for pool.

__global__ __launch_bounds__(256) void k_agg(const float* __restrict__ hwp, const int* __restrict__ rp,
                                             const int* __restrict__ ssrc,
                                             const float* __restrict__ dinv, const float* __restrict__ bias,
                                             float* __restrict__ hout, int n, int pack){
  int b = blockIdx.x;
  int r = b & 7;
  int F = r >> 2;                       // feature half
  int s = (b >> 3) * 4 + (r & 3);       // slot of 4 nodes
  int node = s * 4 + (threadIdx.x >> 6);
  if (node >= n) return;
  int lane = threadIdx.x & 63;
  int ql = lane >> 4;                   // edge slot 0..3
  int fl = lane & 15;                   // feature quad within half
  const v4f* base = (const v4f*)hwp + F * 16 + fl;   // row stride = 32 v4f

  int e0 = rp[node], e1 = rp[node + 1];
  v4f acc = (v4f)(0.f);
  for (int eb = e0; eb < e1; eb += 64){
    int m = e1 - eb; if (m > 64) m = 64;
    int sl = (lane < m) ? ssrc[eb + lane] : 0;
    int mp = m & ~3;
    int j = 0;
    for (; j + 16 <= mp; j += 16){
      int s0 = __shfl(sl, j + ql),     s1 = __shfl(sl, j + 4 + ql);
      int s2 = __shfl(sl, j + 8 + ql), s3 = __shfl(sl, j + 12 + ql);
      v4f v0 = base[(size_t)s0 * 32], v1 = base[(size_t)s1 * 32];
      v4f v2 = base[(size_t)s2 * 32], v3 = base[(size_t)s3 * 32];
      acc += v0; acc += v1; acc += v2; acc += v3;
    }
    if (j + 8 <= mp){
      int s0 = __shfl(sl, j + ql), s1 = __shfl(sl, j + 4 + ql);
      v4f v0 = base[(size_t)s0 * 32], v1 = base[(size_t)s1 * 32];
      acc += v0; acc += v1;
      j += 8;
    }
    if (j + 4 <= mp){
      int s0 = __shfl(sl, j + ql);
      acc += base[(size_t)s0 * 32];
      j += 4;
    }
    if (j < m){
      int s0 = __shfl(sl, j + ql);
      if (j + ql < m){
        acc += base[(size_t)s0 * 32];
      }
    }
  }
  // reduce across the 4 edge slots
  acc.x += __shfl_down(acc.x, 32); acc.y += __shfl_down(acc.y, 32);
  acc.z += __shfl_down(acc.z, 32); acc.w += __shfl_down(acc.w, 32);
  acc.x += __shfl_down(acc.x, 16); acc.y += __shfl_down(acc.y, 16);
  acc.z += __shfl_down(acc.z, 16); acc.w += __shfl_down(acc.w, 16);
  if (lane < 16){
    acc += base[(size_t)node * 32];          // self term (already * dinv[node])
    float di = dinv[node];
    int f = F * 64 + fl * 4;
    v4f bv = *(const v4f*)(bias + f);
    float r0 = tanhf(acc.x * di + bv.x);
    float r1 = tanhf(acc.y * di + bv.y);
    float r2 = tanhf(acc.z * di + bv.z);
    float r3 = tanhf(acc.w * di + bv.w);
    if (pack){
      u16 h0,h1,h2,h3,l0,l1,l2,l3;
      bf_split(r0, h0, l0); bf_split(r1, h1, l1);
      bf_split(r2, h2, l2); bf_split(r3, h3, l3);
      v4u pv;
      pv.x = ((u32)h0 << 16) | l0; pv.y = ((u32)h1 << 16) | l1;
      pv.z = ((u32)h2 << 16) | l2; pv.w = ((u32)h3 << 16) | l3;
      __builtin_nontemporal_store(pv, (v4u*)(hout + (size_t)node * 128 + f));
    } else {
      v4f rr; rr.x = r0; rr.y = r1; rr.z = r2; rr.w = r3;
      __builtin_nontemporal_store(rr, (v4f*)(hout + (size_t)node * 128 + f));
    }
  }
}

// ---------------- pool: stage 1 partial max/sum (float4 lanes, 8 rows/iter) ----------------

__global__ __launch_bounds__(256) void k_pool1(const float* __restrict__ h, const int* __restrict__ gstart,
                                               float* __restrict__ pmx, float* __restrict__ psm){
  int g = blockIdx.x >> 3, s = blockIdx.x & (PSPLIT - 1);
  int t = threadIdx.x;
  int fq = t & 31;             // feature quad
  int rw = t >> 5;             // row slot 0..7
  int i0 = gstart[g], i1 = gstart[g + 1];
  int len = i1 - i0;
  int chunk = (len + PSPLIT - 1) / PSPLIT;
  int a = i0 + s * chunk;
  int b = a + chunk; if (b > i1) b = i1;

  const v4f* hv = (const v4f*)h;
  v4f mx = (v4f)(-INFINITY), sm = (v4f)(0.f);
  for (int i = a + rw; i < b; i += 8){
    v4f v = hv[(size_t)i * 32 + fq];
    mx.x = fmaxf(mx.x, v.x); mx.y = fmaxf(mx.y, v.y);
    mx.z = fmaxf(mx.z, v.z); mx.w = fmaxf(mx.w, v.w);
    sm += v;
  }
  __shared__ v4f smx[8][32], ssm[8][32];
  smx[rw][fq] = mx; ssm[rw][fq] = sm;
  __syncthreads();
  if (rw == 0){
    #pragma unroll
    for (int r2 = 1; r2 < 8; ++r2){
      v4f m2 = smx[r2][fq], s2 = ssm[r2][fq];
      mx.x = fmaxf(mx.x, m2.x); mx.y = fmaxf(mx.y, m2.y);
      mx.z = fmaxf(mx.z, m2.z); mx.w = fmaxf(mx.w, m2.w);
      sm += s2;
    }
    ((v4f*)pmx)[(size_t)blockIdx.x * 32 + fq] = mx;
    ((v4f*)psm)[(size_t)blockIdx.x * 32 + fq] = sm;
  }
}

__global__ __launch_bounds__(128) void k_head(const float* __restrict__ pmx, const float* __restrict__ psm,
                                              const int* __restrict__ gstart,
                                              const float* __restrict__ Wl, const float* __restrict__ bl,
                                              float* __restrict__ out){
  int g = blockIdx.x, f = threadIdx.x;
  float mx = -INFINITY, sm = 0.f;
  #pragma unroll
  for (int s = 0; s < PSPLIT; ++s){
    mx = fmaxf(mx, pmx[((size_t)g * PSPLIT + s) * 128 + f]);
    sm += psm[((size_t)g * PSPLIT + s) * 128 + f];
  }
  int cnt = gstart[g + 1] - gstart[g];
  if (cnt <= 0) mx = 0.f;
  float mn = sm / (float)(cnt > 0 ? cnt : 1);
  float contrib = mx * Wl[f] + mn * Wl[128 + f];
  for (int o = 32; o > 0; o >>= 1) contrib += __shfl_down(contrib, o);
  __shared__ float sred[2];
  if ((f & 63) == 0) sred[f >> 6] = contrib;
  __syncthreads();
  if (f == 0) out[g] = sred[0] + sred[1] + bl[0];
}

// ---------------- launch ----------------

extern "C" void kernel_launch(void* const* d_in, const int* in_sizes, int n_in,
                              void* d_out, int out_size, void* d_ws, size_t ws_size,
                              hipStream_t stream){
  const float* x     = (const float*)d_in[0];
  const int*   ei    = (const int*)d_in[1];
  const int*   batch = (const int*)d_in[2];
  const float* W[4]  = {(const float*)d_in[3], (const float*)d_in[5], (const float*)d_in[7], (const float*)d_in[9]};
  const float* B[4]  = {(const float*)d_in[4], (const float*)d_in[6], (const float*)d_in[8], (const float*)d_in[10]};
  const float* Wl    = (const float*)d_in[11];
  const float* bl    = (const float*)d_in[12];
  float* out = (float*)d_out;

  int N = in_sizes[0] / 128;
  int E = in_sizes[1] / 2;
  int G = out_size;
  int NB = (N + BW - 1) >> BSH;

  char* ws = (char*)d_ws;
  size_t off = 0;
  auto alloc = [&](size_t bytes) -> void* {
    void* p = ws + off; off = align_up(off + bytes, 256); return p;
  };
  float* dinv  = (float*)alloc((size_t)N * 4);
  int*   rp    = (int*)  alloc((size_t)(N + 1) * 4);
  int*   bcnt  = (int*)  alloc((size_t)(NB + 1) * 4);
  int*   boff  = (int*)  alloc((size_t)(NB + 1) * 4);
  int*   bfill = (int*)  alloc((size_t)NB * 32 * 4);
  int*   gst   = (int*)  alloc((size_t)(G + 1) * 4);
  int*   ssrc  = (int*)  alloc((size_t)E * 4);
  u16*   wth   = (u16*)  alloc((size_t)4 * 16384 * 2);
  u16*   wtl   = (u16*)  alloc((size_t)4 * 16384 * 2);
  float* pmx   = (float*)alloc((size_t)G * PSPLIT * 128 * 4);
  float* psm   = (float*)alloc((size_t)G * PSPLIT * 128 * 4);
  float* hw    = (float*)alloc((size_t)N * 128 * 4);
  float* h     = (float*)alloc((size_t)N * 128 * 4);
  unsigned* tmp = (unsigned*)hw;   // alias: tmp dead before first gemm writes hw

  hipMemsetAsync(bcnt, 0, (size_t)(NB + 1) * 4, stream);
  hipMemsetAsync(bfill, 0, (size_t)NB * 32 * 4, stream);

  int gE = (E + 255) / 256;
  k_cvtw <<<256, 256, 0, stream>>>(W[0], W[1], W[2], W[3], wth, wtl);
  k_bhist<<<128, 256, NB * 4, stream>>>(ei + E, bcnt, E, NB, batch, gst, N, G);
  k_bscan<<<1, 256, 0, stream>>>(bcnt, boff, NB, E, rp, N);
  k_bscat<<<gE, 256, 0, stream>>>(ei, boff, bfill, tmp, E);
  k_bfin <<<NB, 256, 0, stream>>>(tmp, boff, ssrc, rp, dinv, N);

  int gemmG = (N + 127) / 128;
  int slots = (N + 3) / 4;                 // (node-quad) slots per feature half
  int aggG  = 8 * ((slots + 3) / 4);       // 2-way static feature split
  const float* hin = x;
  for (int l = 0; l < 4; ++l){
    k_gemm<<<gemmG, 256, 0, stream>>>(hin, wth + (l << 14), wtl + (l << 14), dinv, hw, N, l > 0);
    k_agg <<<aggG, 256, 0, stream>>>(hw, rp, ssrc, dinv, B[l], h, N, l < 3);
    hin = h;
  }
  k_pool1<<<G * PSPLIT, 256, 0, stream>>>(h, gst, pmx, psm);
  k_head <<<G, 128, 0, stream>>>(pmx, psm, gst, Wl, bl, out);
}